// Round 1
// baseline (893.235 us; speedup 1.0000x reference)
//
#include <hip/hip_runtime.h>
#include <math.h>

typedef short bf16x8 __attribute__((ext_vector_type(8)));
typedef float f32x4 __attribute__((ext_vector_type(4)));
typedef unsigned short u16;

// ---------------------------------------------------------------- helpers
__device__ __forceinline__ u16 f2bf(float f) {
    union { float f; unsigned u; } v; v.f = f;
    unsigned r = v.u + 0x7fffu + ((v.u >> 16) & 1u);
    return (u16)(r >> 16);
}

__device__ __forceinline__ void gload_lds16(const void* g, void* l) {
    __builtin_amdgcn_global_load_lds((const __attribute__((address_space(1))) void*)g,
                                     (__attribute__((address_space(3))) void*)l, 16, 0, 0);
}

// ---------------------------------------------------------------- transpose+cvt
// in: [R][C] f32 (slab z), out: [C][R] bf16
__global__ __launch_bounds__(256)
void transpose_cvt(const float* __restrict__ in, u16* __restrict__ out, int R, int C)
{
    __shared__ float tile[64][65];
    const size_t slab = (size_t)blockIdx.z * R * C;
    const float* ip = in + slab;
    u16* op = out + slab;
    const int r0 = blockIdx.y * 64, c0 = blockIdx.x * 64;
    const int t = threadIdx.x;
    const int tr = t >> 6, tc = t & 63;
    #pragma unroll
    for (int i = 0; i < 16; ++i)
        tile[tr + i*4][tc] = ip[(size_t)(r0 + tr + i*4)*C + c0 + tc];
    __syncthreads();
    #pragma unroll
    for (int i = 0; i < 16; ++i)
        op[(size_t)(c0 + tr + i*4)*R + r0 + tc] = f2bf(tile[tc][tr + i*4]);
}

// ---------------------------------------------------------------- layernorm (f32 in -> bf16 out)
__global__ __launch_bounds__(256)
void ln_kernel(const float* __restrict__ x, const float* __restrict__ g,
               const float* __restrict__ b, u16* __restrict__ out)
{
    const int row = blockIdx.x;
    const int t = threadIdx.x;
    const float4 v = ((const float4*)(x + (size_t)row*1024))[t];
    float s = v.x + v.y + v.z + v.w;
    float ss = v.x*v.x + v.y*v.y + v.z*v.z + v.w*v.w;
    #pragma unroll
    for (int m = 1; m < 64; m <<= 1) {
        s  += __shfl_xor(s, m);
        ss += __shfl_xor(ss, m);
    }
    __shared__ float red[8];
    const int wave = t >> 6;
    if ((t & 63) == 0) { red[wave] = s; red[4 + wave] = ss; }
    __syncthreads();
    s  = red[0] + red[1] + red[2] + red[3];
    ss = red[4] + red[5] + red[6] + red[7];
    const float mu = s * (1.f/1024.f);
    const float rs = rsqrtf(ss * (1.f/1024.f) - mu*mu + 1e-5f);
    const float4 gv = ((const float4*)g)[t];
    const float4 bv = ((const float4*)b)[t];
    ushort4 ov;
    ov.x = f2bf((v.x - mu)*rs*gv.x + bv.x);
    ov.y = f2bf((v.y - mu)*rs*gv.y + bv.y);
    ov.z = f2bf((v.z - mu)*rs*gv.z + bv.z);
    ov.w = f2bf((v.w - mu)*rs*gv.w + bv.w);
    ((ushort4*)(out + (size_t)row*1024))[t] = ov;
}

// ---------------------------------------------------------------- GEMM (m97 structure)
// A [M=8192][K] bf16 row-major, BT [N][K] bf16 row-major.
// EPI 0: QKV split -> qbuf/kbuf (bf16 [B,T,1024]) + vt (bf16 [B,H,64,T])
// EPI 1: out_f32 = acc + bias + res          (proj, fc2)
// EPI 2: out_bf16 = relu(acc + bias)          (fc1)
template<int N, int K, int EPI>
__global__ __launch_bounds__(256)
void gemm_kernel(const u16* __restrict__ A, const u16* __restrict__ BT,
                 float* __restrict__ out_f32, u16* __restrict__ out_bf16,
                 const float* __restrict__ bias, const float* __restrict__ res,
                 u16* __restrict__ qbuf, u16* __restrict__ kbuf, u16* __restrict__ vt)
{
    __shared__ u16 As[128*32];
    __shared__ u16 Bs[128*32];
    const int t = threadIdx.x;
    const int wave = t >> 6;
    const int lane = t & 63;
    const int l15 = lane & 15, lg = lane >> 4;
    const int m0 = blockIdx.x * 128, n0 = blockIdx.y * 128;
    const int wr = wave >> 1, wc = wave & 1;
    f32x4 acc[4][4] = {};

    const int srow = t >> 2;       // 0..63
    const int sce  = (t & 3) * 8;  // k-elem offset of this thread's 16B
    for (int k0 = 0; k0 < K; k0 += 32) {
        #pragma unroll
        for (int i = 0; i < 2; ++i) {
            const u16* ga = A  + (size_t)(m0 + i*64 + srow) * K + k0 + sce;
            const u16* gb = BT + (size_t)(n0 + i*64 + srow) * K + k0 + sce;
            gload_lds16(ga, As + i*2048 + wave*512);
            gload_lds16(gb, Bs + i*2048 + wave*512);
        }
        __syncthreads();
        bf16x8 af[4], bfr[4];
        #pragma unroll
        for (int mi = 0; mi < 4; ++mi)
            af[mi] = *(const bf16x8*)(As + (wr*64 + mi*16 + l15)*32 + lg*8);
        #pragma unroll
        for (int ni = 0; ni < 4; ++ni)
            bfr[ni] = *(const bf16x8*)(Bs + (wc*64 + ni*16 + l15)*32 + lg*8);
        #pragma unroll
        for (int mi = 0; mi < 4; ++mi)
            #pragma unroll
            for (int ni = 0; ni < 4; ++ni)
                acc[mi][ni] = __builtin_amdgcn_mfma_f32_16x16x32_bf16(af[mi], bfr[ni], acc[mi][ni], 0, 0, 0);
        __syncthreads();
    }

    #pragma unroll
    for (int mi = 0; mi < 4; ++mi) {
        #pragma unroll
        for (int ni = 0; ni < 4; ++ni) {
            const int gc = n0 + wc*64 + ni*16 + l15;
            #pragma unroll
            for (int j = 0; j < 4; ++j) {
                const int gr = m0 + wr*64 + mi*16 + lg*4 + j;
                float v = acc[mi][ni][j];
                if constexpr (EPI == 0) {
                    u16 bv = f2bf(v);
                    if (gc < 1024) {
                        qbuf[(size_t)gr*1024 + gc] = bv;
                    } else if (gc < 2048) {
                        kbuf[(size_t)gr*1024 + (gc - 1024)] = bv;
                    } else {
                        const int hd = gc - 2048;
                        const int bb = gr >> 11, tt = gr & 2047;
                        vt[(size_t)((bb*16 + (hd >> 6))*64 + (hd & 63))*2048 + tt] = bv;
                    }
                } else if constexpr (EPI == 1) {
                    out_f32[(size_t)gr*N + gc] = v + bias[gc] + res[(size_t)gr*N + gc];
                } else {
                    out_bf16[(size_t)gr*N + gc] = f2bf(fmaxf(v + bias[gc], 0.f));
                }
            }
        }
    }
}

// ---------------------------------------------------------------- flash attention
// q,k: bf16 [B,T,1024] (col = h*64+d);  vt: bf16 [B*H][64][2048];  out: bf16 [B,T,1024]
__global__ __launch_bounds__(256)
void attn_kernel(const u16* __restrict__ q, const u16* __restrict__ k,
                 const u16* __restrict__ vt, u16* __restrict__ out)
{
    __shared__ u16 Plds[4][16*64];
    const int qb = blockIdx.x;           // query tile of 64
    const int bh = blockIdx.y;           // b*16+h
    const int b = bh >> 4, h = bh & 15;
    const int wave = threadIdx.x >> 6, lane = threadIdx.x & 63;
    const int l15 = lane & 15, lg = lane >> 4;
    const int q0 = qb*64 + wave*16;      // this wave's 16 queries
    const u16* Qp = q + (size_t)b*2048*1024 + h*64;
    const u16* Kp = k + (size_t)b*2048*1024 + h*64;
    const u16* Vp = vt + (size_t)bh*64*2048;
    u16* pl = Plds[wave];

    bf16x8 qf[2];
    #pragma unroll
    for (int kk = 0; kk < 2; ++kk)
        qf[kk] = *(const bf16x8*)(Qp + (size_t)(q0 + l15)*1024 + kk*32 + lg*8);

    f32x4 o[4] = {};
    float mprev[4], lsum[4];
    #pragma unroll
    for (int j = 0; j < 4; ++j) { mprev[j] = -INFINITY; lsum[j] = 0.f; }
    const int swz = (l15 & 7) * 8;

    for (int kt = 0; kt <= qb; ++kt) {
        const int key0 = kt * 64;
        f32x4 s[4] = {};
        #pragma unroll
        for (int n = 0; n < 4; ++n)
            #pragma unroll
            for (int kk = 0; kk < 2; ++kk) {
                bf16x8 kf = *(const bf16x8*)(Kp + (size_t)(key0 + n*16 + l15)*1024 + kk*32 + lg*8);
                s[n] = __builtin_amdgcn_mfma_f32_16x16x32_bf16(qf[kk], kf, s[n], 0, 0, 0);
            }
        const bool diag = (kt == qb);
        float tm[4] = {-INFINITY, -INFINITY, -INFINITY, -INFINITY};
        #pragma unroll
        for (int n = 0; n < 4; ++n)
            #pragma unroll
            for (int j = 0; j < 4; ++j) {
                float sv = s[n][j] * 0.03125f;   // * C^-0.5 = 1/32
                if (diag && (key0 + n*16 + l15 > q0 + lg*4 + j)) sv = -INFINITY;
                s[n][j] = sv;
                tm[j] = fmaxf(tm[j], sv);
            }
        #pragma unroll
        for (int m = 1; m < 16; m <<= 1)
            #pragma unroll
            for (int j = 0; j < 4; ++j)
                tm[j] = fmaxf(tm[j], __shfl_xor(tm[j], m, 16));
        float alpha[4], rsum[4];
        #pragma unroll
        for (int j = 0; j < 4; ++j) {
            float mn = fmaxf(mprev[j], tm[j]);
            alpha[j] = __expf(mprev[j] - mn);
            mprev[j] = mn;
            rsum[j] = 0.f;
        }
        #pragma unroll
        for (int n = 0; n < 4; ++n)
            #pragma unroll
            for (int j = 0; j < 4; ++j) {
                float pv = __expf(s[n][j] - mprev[j]);
                rsum[j] += pv;
                const int qq = lg*4 + j;
                pl[qq*64 + ((n*16 + l15) ^ ((qq & 7) * 8))] = f2bf(pv);
            }
        #pragma unroll
        for (int m = 1; m < 16; m <<= 1)
            #pragma unroll
            for (int j = 0; j < 4; ++j)
                rsum[j] += __shfl_xor(rsum[j], m, 16);
        #pragma unroll
        for (int j = 0; j < 4; ++j)
            lsum[j] = lsum[j]*alpha[j] + rsum[j];
        #pragma unroll
        for (int dn = 0; dn < 4; ++dn)
            #pragma unroll
            for (int j = 0; j < 4; ++j)
                o[dn][j] *= alpha[j];
        bf16x8 pf[2];
        #pragma unroll
        for (int kk = 0; kk < 2; ++kk)
            pf[kk] = *(const bf16x8*)(pl + l15*64 + ((kk*32 + lg*8) ^ swz));
        #pragma unroll
        for (int dn = 0; dn < 4; ++dn)
            #pragma unroll
            for (int kk = 0; kk < 2; ++kk) {
                bf16x8 vf = *(const bf16x8*)(Vp + (size_t)(dn*16 + l15)*2048 + key0 + kk*32 + lg*8);
                o[dn] = __builtin_amdgcn_mfma_f32_16x16x32_bf16(pf[kk], vf, o[dn], 0, 0, 0);
            }
    }
    #pragma unroll
    for (int dn = 0; dn < 4; ++dn)
        #pragma unroll
        for (int j = 0; j < 4; ++j) {
            float v = o[dn][j] / lsum[j];
            out[(size_t)(b*2048 + q0 + lg*4 + j)*1024 + h*64 + dn*16 + l15] = f2bf(v);
        }
}

// ---------------------------------------------------------------- launch
#define MB(x) ((size_t)(x) << 20)

extern "C" void kernel_launch(void* const* d_in, const int* in_sizes, int n_in,
                              void* d_out, int out_size, void* d_ws, size_t ws_size,
                              hipStream_t stream) {
    const float* x      = (const float*)d_in[0];
    const float* Wq     = (const float*)d_in[1];
    const float* Wk     = (const float*)d_in[2];
    const float* Wv     = (const float*)d_in[3];
    const float* Wproj  = (const float*)d_in[4];
    const float* bproj  = (const float*)d_in[5];
    const float* ln1_g  = (const float*)d_in[6];
    const float* ln1_b  = (const float*)d_in[7];
    const float* ln2_g  = (const float*)d_in[8];
    const float* ln2_b  = (const float*)d_in[9];
    const float* W1     = (const float*)d_in[10];
    const float* b1     = (const float*)d_in[11];
    const float* W2     = (const float*)d_in[12];
    const float* b2     = (const float*)d_in[13];
    float* out = (float*)d_out;

    char* ws = (char*)d_ws;
    u16*  h      = (u16*)(ws + MB(0));     // 16 MB   (reused as h2)
    u16*  qbuf   = (u16*)(ws + MB(16));    // 16 MB
    u16*  kbuf   = (u16*)(ws + MB(32));    // 16 MB
    u16*  vt     = (u16*)(ws + MB(48));    // 16 MB
    u16*  attn   = (u16*)(ws + MB(64));    // 16 MB
    float* x2    = (float*)(ws + MB(80));  // 32 MB
    u16*  BTqkv  = (u16*)(ws + MB(112));   // 6 MB  [3072][1024]
    u16*  BTproj = (u16*)(ws + MB(118));   // 2 MB  [1024][1024]
    u16*  BT1    = (u16*)(ws + MB(120));   // 8 MB  [4096][1024]
    u16*  BT2    = (u16*)(ws + MB(128));   // 8 MB  [1024][4096]
    u16*  ff     = (u16*)(ws + MB(16));    // 64 MB, reuses qbuf..attn (dead by then)
    u16*  h2     = h;

    // weights -> bf16, transposed to [N][K]
    transpose_cvt<<<dim3(1,16,16),  256, 0, stream>>>(Wq,    BTqkv,             1024, 64);
    transpose_cvt<<<dim3(1,16,16),  256, 0, stream>>>(Wk,    BTqkv + (1<<20),   1024, 64);
    transpose_cvt<<<dim3(1,16,16),  256, 0, stream>>>(Wv,    BTqkv + (2<<20),   1024, 64);
    transpose_cvt<<<dim3(16,16,1),  256, 0, stream>>>(Wproj, BTproj,            1024, 1024);
    transpose_cvt<<<dim3(64,16,1),  256, 0, stream>>>(W1,    BT1,               1024, 4096);
    transpose_cvt<<<dim3(16,64,1),  256, 0, stream>>>(W2,    BT2,               4096, 1024);

    // LN1
    ln_kernel<<<8192, 256, 0, stream>>>(x, ln1_g, ln1_b, h);
    // QKV
    gemm_kernel<3072,1024,0><<<dim3(64,24), 256, 0, stream>>>(h, BTqkv, nullptr, nullptr,
        nullptr, nullptr, qbuf, kbuf, vt);
    // attention
    attn_kernel<<<dim3(32,64), 256, 0, stream>>>(qbuf, kbuf, vt, attn);
    // proj + residual (x) -> x2
    gemm_kernel<1024,1024,1><<<dim3(64,8), 256, 0, stream>>>(attn, BTproj, x2, nullptr,
        bproj, x, nullptr, nullptr, nullptr);
    // LN2
    ln_kernel<<<8192, 256, 0, stream>>>(x2, ln2_g, ln2_b, h2);
    // FC1 + relu
    gemm_kernel<4096,1024,2><<<dim3(64,32), 256, 0, stream>>>(h2, BT1, nullptr, ff,
        b1, nullptr, nullptr, nullptr, nullptr);
    // FC2 + residual (x2) -> out
    gemm_kernel<1024,4096,1><<<dim3(64,8), 256, 0, stream>>>(ff, BT2, out, nullptr,
        b2, x2, nullptr, nullptr, nullptr);
}

// Round 2
// 767.645 us; speedup vs baseline: 1.1636x; 1.1636x over previous
//
#include <hip/hip_runtime.h>
#include <math.h>

typedef short bf16x8 __attribute__((ext_vector_type(8)));
typedef float f32x4 __attribute__((ext_vector_type(4)));
typedef unsigned short u16;

// ---------------------------------------------------------------- helpers
__device__ __forceinline__ u16 f2bf(float f) {
    union { float f; unsigned u; } v; v.f = f;
    unsigned r = v.u + 0x7fffu + ((v.u >> 16) & 1u);
    return (u16)(r >> 16);
}

__device__ __forceinline__ void gload_lds16(const void* g, void* l) {
    __builtin_amdgcn_global_load_lds((const __attribute__((address_space(1))) void*)g,
                                     (__attribute__((address_space(3))) void*)l, 16, 0, 0);
}

// ---------------------------------------------------------------- transpose+cvt
__global__ __launch_bounds__(256)
void transpose_cvt(const float* __restrict__ in, u16* __restrict__ out, int R, int C)
{
    __shared__ float tile[64][65];
    const size_t slab = (size_t)blockIdx.z * R * C;
    const float* ip = in + slab;
    u16* op = out + slab;
    const int r0 = blockIdx.y * 64, c0 = blockIdx.x * 64;
    const int t = threadIdx.x;
    const int tr = t >> 6, tc = t & 63;
    #pragma unroll
    for (int i = 0; i < 16; ++i)
        tile[tr + i*4][tc] = ip[(size_t)(r0 + tr + i*4)*C + c0 + tc];
    __syncthreads();
    #pragma unroll
    for (int i = 0; i < 16; ++i)
        op[(size_t)(c0 + tr + i*4)*R + r0 + tc] = f2bf(tile[tc][tr + i*4]);
}

// ---------------------------------------------------------------- layernorm
__global__ __launch_bounds__(256)
void ln_kernel(const float* __restrict__ x, const float* __restrict__ g,
               const float* __restrict__ b, u16* __restrict__ out)
{
    const int row = blockIdx.x;
    const int t = threadIdx.x;
    const float4 v = ((const float4*)(x + (size_t)row*1024))[t];
    float s = v.x + v.y + v.z + v.w;
    float ss = v.x*v.x + v.y*v.y + v.z*v.z + v.w*v.w;
    #pragma unroll
    for (int m = 1; m < 64; m <<= 1) {
        s  += __shfl_xor(s, m);
        ss += __shfl_xor(ss, m);
    }
    __shared__ float red[8];
    const int wave = t >> 6;
    if ((t & 63) == 0) { red[wave] = s; red[4 + wave] = ss; }
    __syncthreads();
    s  = red[0] + red[1] + red[2] + red[3];
    ss = red[4] + red[5] + red[6] + red[7];
    const float mu = s * (1.f/1024.f);
    const float rs = rsqrtf(ss * (1.f/1024.f) - mu*mu + 1e-5f);
    const float4 gv = ((const float4*)g)[t];
    const float4 bv = ((const float4*)b)[t];
    ushort4 ov;
    ov.x = f2bf((v.x - mu)*rs*gv.x + bv.x);
    ov.y = f2bf((v.y - mu)*rs*gv.y + bv.y);
    ov.z = f2bf((v.z - mu)*rs*gv.z + bv.z);
    ov.w = f2bf((v.w - mu)*rs*gv.w + bv.w);
    ((ushort4*)(out + (size_t)row*1024))[t] = ov;
}

// ---------------------------------------------------------------- GEMM (m97 structure + XCD swizzle)
// A [8192][K] bf16 row-major, BT [N][K] bf16 row-major. GX = 64 M-tiles.
template<int NWG, int N, int K, int EPI>
__global__ __launch_bounds__(256)
void gemm_kernel(const u16* __restrict__ A, const u16* __restrict__ BT,
                 float* __restrict__ out_f32, u16* __restrict__ out_bf16,
                 const float* __restrict__ bias, const float* __restrict__ res,
                 u16* __restrict__ qbuf, u16* __restrict__ kbuf, u16* __restrict__ vt)
{
    __shared__ u16 As[128*32];
    __shared__ u16 Bs[128*32];
    const int bid = blockIdx.x;
    const int tid = ((bid & 7) * (NWG / 8)) + (bid >> 3);   // bijective XCD swizzle
    const int m0 = (tid & 63) * 128;
    const int n0 = (tid >> 6) * 128;
    const int t = threadIdx.x;
    const int wave = t >> 6;
    const int lane = t & 63;
    const int l15 = lane & 15, lg = lane >> 4;
    const int wr = wave >> 1, wc = wave & 1;
    f32x4 acc[4][4] = {};

    const int srow = t >> 2;
    const int sce  = (t & 3) * 8;
    for (int k0 = 0; k0 < K; k0 += 32) {
        #pragma unroll
        for (int i = 0; i < 2; ++i) {
            const u16* ga = A  + (size_t)(m0 + i*64 + srow) * K + k0 + sce;
            const u16* gb = BT + (size_t)(n0 + i*64 + srow) * K + k0 + sce;
            gload_lds16(ga, As + i*2048 + wave*512);
            gload_lds16(gb, Bs + i*2048 + wave*512);
        }
        __syncthreads();
        bf16x8 af[4], bfr[4];
        #pragma unroll
        for (int mi = 0; mi < 4; ++mi)
            af[mi] = *(const bf16x8*)(As + (wr*64 + mi*16 + l15)*32 + lg*8);
        #pragma unroll
        for (int ni = 0; ni < 4; ++ni)
            bfr[ni] = *(const bf16x8*)(Bs + (wc*64 + ni*16 + l15)*32 + lg*8);
        #pragma unroll
        for (int mi = 0; mi < 4; ++mi)
            #pragma unroll
            for (int ni = 0; ni < 4; ++ni)
                acc[mi][ni] = __builtin_amdgcn_mfma_f32_16x16x32_bf16(af[mi], bfr[ni], acc[mi][ni], 0, 0, 0);
        __syncthreads();
    }

    #pragma unroll
    for (int mi = 0; mi < 4; ++mi) {
        #pragma unroll
        for (int ni = 0; ni < 4; ++ni) {
            const int gc = n0 + wc*64 + ni*16 + l15;
            #pragma unroll
            for (int j = 0; j < 4; ++j) {
                const int gr = m0 + wr*64 + mi*16 + lg*4 + j;
                float v = acc[mi][ni][j];
                if constexpr (EPI == 0) {
                    u16 bv = f2bf(v);
                    if (gc < 1024) {
                        qbuf[(size_t)gr*1024 + gc] = bv;
                    } else if (gc < 2048) {
                        kbuf[(size_t)gr*1024 + (gc - 1024)] = bv;
                    } else {
                        const int hd = gc - 2048;
                        const int bb = gr >> 11, tt = gr & 2047;
                        vt[(size_t)((bb*16 + (hd >> 6))*64 + (hd & 63))*2048 + tt] = bv;
                    }
                } else if constexpr (EPI == 1) {
                    out_f32[(size_t)gr*N + gc] = v + bias[gc] + res[(size_t)gr*N + gc];
                } else {
                    out_bf16[(size_t)gr*N + gc] = f2bf(fmaxf(v + bias[gc], 0.f));
                }
            }
        }
    }
}

// ---------------------------------------------------------------- flash attention v2
// 128 queries/block, 4 waves x 32q, K/V tiles double-buffered in LDS (swizzled),
// counted-vmcnt prefetch, raw s_barrier.
__global__ __launch_bounds__(256)
void attn_kernel(const u16* __restrict__ q, const u16* __restrict__ k,
                 const u16* __restrict__ vt, u16* __restrict__ out)
{
    __shared__ u16 Ks[2][4096];    // [64 key][64 d], XOR-swizzled rows of 128B
    __shared__ u16 Vs[2][4096];    // [64 d][64 key], XOR-swizzled
    __shared__ u16 Plds[4][1024];  // per-wave [16 q][64 key], swizzled

    const int qb = blockIdx.x;              // 0..15 (128 queries each)
    const int bh = blockIdx.y;
    const int b = bh >> 4, h = bh & 15;
    const int wave = threadIdx.x >> 6, lane = threadIdx.x & 63;
    const int l15 = lane & 15, lg = lane >> 4;
    const int q0 = qb*128 + wave*32;
    const u16* Qp = q + (size_t)b*2048*1024 + h*64;
    const u16* Kp = k + (size_t)b*2048*1024 + h*64;
    const u16* Vp = vt + (size_t)bh*64*2048;
    u16* pl = Plds[wave];

    // Q fragments: 2 frags (16 rows each) x 2 k-chunks
    bf16x8 qf[2][2];
    #pragma unroll
    for (int mi = 0; mi < 2; ++mi)
        #pragma unroll
        for (int kk = 0; kk < 2; ++kk)
            qf[mi][kk] = *(const bf16x8*)(Qp + (size_t)(q0 + mi*16 + l15)*1024 + kk*32 + lg*8);

    // staging geometry: thread stages 16B; dest linear L = chunk*1024 + lane*16
    const int srow0 = wave*8 + (lane >> 3);                    // dest row (r=0 round)
    const int scol  = ((lane & 7) ^ (srow0 & 7)) << 3;         // pre-swizzled src col (u16)
    const int swzf  = (l15 & 7) << 4;                          // fragment-read swizzle (bytes)
    const int swzp  = (l15 & 7) << 3;                          // P-read swizzle (u16)

    f32x4 o[2][4] = {};
    float mprev[2][4], lsum[2][4];
    #pragma unroll
    for (int mi = 0; mi < 2; ++mi)
        #pragma unroll
        for (int j = 0; j < 4; ++j) { mprev[mi][j] = -INFINITY; lsum[mi][j] = 0.f; }

    const int nkt = 2*qb + 2;

    #define STAGE(buf, key0_) do { \
        gload_lds16(Kp + (size_t)((key0_) + srow0)*1024 + scol,      &Ks[buf][wave*512]); \
        gload_lds16(Kp + (size_t)((key0_) + srow0 + 32)*1024 + scol, &Ks[buf][(4+wave)*512]); \
        gload_lds16(Vp + (size_t)srow0*2048 + (key0_) + scol,        &Vs[buf][wave*512]); \
        gload_lds16(Vp + (size_t)(srow0+32)*2048 + (key0_) + scol,   &Vs[buf][(4+wave)*512]); \
    } while (0)

    STAGE(0, 0);

    for (int kt = 0; kt < nkt; ++kt) {
        const int cur = kt & 1;
        const int key0 = kt * 64;
        if (kt + 1 < nkt) {
            STAGE(cur ^ 1, key0 + 64);
            asm volatile("s_waitcnt vmcnt(4)" ::: "memory");
        } else {
            asm volatile("s_waitcnt vmcnt(0)" ::: "memory");
        }
        __builtin_amdgcn_s_barrier();
        __builtin_amdgcn_sched_barrier(0);

        if (key0 <= q0 + 31) {
            #pragma unroll
            for (int mi = 0; mi < 2; ++mi) {
                if (key0 > q0 + mi*16 + 15) continue;   // frag fully masked
                // ---- S = Q K^T
                f32x4 s[4] = {};
                #pragma unroll
                for (int n = 0; n < 4; ++n)
                    #pragma unroll
                    for (int kk = 0; kk < 2; ++kk) {
                        const int row = n*16 + l15;
                        bf16x8 kf = *(const bf16x8*)((const char*)&Ks[cur][0]
                                        + row*128 + ((kk*64 + lg*16) ^ swzf));
                        s[n] = __builtin_amdgcn_mfma_f32_16x16x32_bf16(qf[mi][kk], kf, s[n], 0, 0, 0);
                    }
                // ---- mask + scale + row max
                const bool domask = (key0 + 63) > (q0 + mi*16);
                float tm[4] = {-INFINITY, -INFINITY, -INFINITY, -INFINITY};
                #pragma unroll
                for (int n = 0; n < 4; ++n)
                    #pragma unroll
                    for (int j = 0; j < 4; ++j) {
                        float sv = s[n][j] * 0.03125f;
                        if (domask && (key0 + n*16 + l15 > q0 + mi*16 + lg*4 + j)) sv = -INFINITY;
                        s[n][j] = sv;
                        tm[j] = fmaxf(tm[j], sv);
                    }
                #pragma unroll
                for (int m = 1; m < 16; m <<= 1)
                    #pragma unroll
                    for (int j = 0; j < 4; ++j)
                        tm[j] = fmaxf(tm[j], __shfl_xor(tm[j], m, 16));
                float alpha[4], rsum[4];
                #pragma unroll
                for (int j = 0; j < 4; ++j) {
                    float mn = fmaxf(mprev[mi][j], tm[j]);
                    alpha[j] = __expf(mprev[mi][j] - mn);
                    mprev[mi][j] = mn;
                    rsum[j] = 0.f;
                }
                // ---- P = exp(S - m), write to LDS (swizzled)
                #pragma unroll
                for (int n = 0; n < 4; ++n)
                    #pragma unroll
                    for (int j = 0; j < 4; ++j) {
                        float pv = __expf(s[n][j] - mprev[mi][j]);
                        rsum[j] += pv;
                        const int qq = lg*4 + j;
                        pl[qq*64 + ((n*16 + l15) ^ ((qq & 7) * 8))] = f2bf(pv);
                    }
                #pragma unroll
                for (int m = 1; m < 16; m <<= 1)
                    #pragma unroll
                    for (int j = 0; j < 4; ++j)
                        rsum[j] += __shfl_xor(rsum[j], m, 16);
                #pragma unroll
                for (int j = 0; j < 4; ++j)
                    lsum[mi][j] = lsum[mi][j]*alpha[j] + rsum[j];
                #pragma unroll
                for (int dn = 0; dn < 4; ++dn)
                    #pragma unroll
                    for (int j = 0; j < 4; ++j)
                        o[mi][dn][j] *= alpha[j];
                // ---- PV
                bf16x8 pf[2];
                #pragma unroll
                for (int kk = 0; kk < 2; ++kk)
                    pf[kk] = *(const bf16x8*)(pl + l15*64 + ((kk*32 + lg*8) ^ swzp));
                #pragma unroll
                for (int dn = 0; dn < 4; ++dn)
                    #pragma unroll
                    for (int kk = 0; kk < 2; ++kk) {
                        const int row = dn*16 + l15;
                        bf16x8 vf = *(const bf16x8*)((const char*)&Vs[cur][0]
                                        + row*128 + ((kk*64 + lg*16) ^ swzf));
                        o[mi][dn] = __builtin_amdgcn_mfma_f32_16x16x32_bf16(pf[kk], vf, o[mi][dn], 0, 0, 0);
                    }
            }
        }
        __builtin_amdgcn_sched_barrier(0);
        __builtin_amdgcn_s_barrier();
    }
    #undef STAGE

    #pragma unroll
    for (int mi = 0; mi < 2; ++mi)
        #pragma unroll
        for (int dn = 0; dn < 4; ++dn)
            #pragma unroll
            for (int j = 0; j < 4; ++j) {
                float v = o[mi][dn][j] / lsum[mi][j];
                out[(size_t)(b*2048 + q0 + mi*16 + lg*4 + j)*1024 + h*64 + dn*16 + l15] = f2bf(v);
            }
}

// ---------------------------------------------------------------- launch
#define MB(x) ((size_t)(x) << 20)

extern "C" void kernel_launch(void* const* d_in, const int* in_sizes, int n_in,
                              void* d_out, int out_size, void* d_ws, size_t ws_size,
                              hipStream_t stream) {
    const float* x      = (const float*)d_in[0];
    const float* Wq     = (const float*)d_in[1];
    const float* Wk     = (const float*)d_in[2];
    const float* Wv     = (const float*)d_in[3];
    const float* Wproj  = (const float*)d_in[4];
    const float* bproj  = (const float*)d_in[5];
    const float* ln1_g  = (const float*)d_in[6];
    const float* ln1_b  = (const float*)d_in[7];
    const float* ln2_g  = (const float*)d_in[8];
    const float* ln2_b  = (const float*)d_in[9];
    const float* W1     = (const float*)d_in[10];
    const float* b1     = (const float*)d_in[11];
    const float* W2     = (const float*)d_in[12];
    const float* b2     = (const float*)d_in[13];
    float* out = (float*)d_out;

    char* ws = (char*)d_ws;
    u16*  h      = (u16*)(ws + MB(0));
    u16*  qbuf   = (u16*)(ws + MB(16));
    u16*  kbuf   = (u16*)(ws + MB(32));
    u16*  vt     = (u16*)(ws + MB(48));
    u16*  attn   = (u16*)(ws + MB(64));
    float* x2    = (float*)(ws + MB(80));
    u16*  BTqkv  = (u16*)(ws + MB(112));
    u16*  BTproj = (u16*)(ws + MB(118));
    u16*  BT1    = (u16*)(ws + MB(120));
    u16*  BT2    = (u16*)(ws + MB(128));
    u16*  ff     = (u16*)(ws + MB(16));
    u16*  h2     = h;

    transpose_cvt<<<dim3(1,16,16),  256, 0, stream>>>(Wq,    BTqkv,             1024, 64);
    transpose_cvt<<<dim3(1,16,16),  256, 0, stream>>>(Wk,    BTqkv + (1<<20),   1024, 64);
    transpose_cvt<<<dim3(1,16,16),  256, 0, stream>>>(Wv,    BTqkv + (2<<20),   1024, 64);
    transpose_cvt<<<dim3(16,16,1),  256, 0, stream>>>(Wproj, BTproj,            1024, 1024);
    transpose_cvt<<<dim3(64,16,1),  256, 0, stream>>>(W1,    BT1,               1024, 4096);
    transpose_cvt<<<dim3(16,64,1),  256, 0, stream>>>(W2,    BT2,               4096, 1024);

    ln_kernel<<<8192, 256, 0, stream>>>(x, ln1_g, ln1_b, h);
    gemm_kernel<1536,3072,1024,0><<<1536, 256, 0, stream>>>(h, BTqkv, nullptr, nullptr,
        nullptr, nullptr, qbuf, kbuf, vt);
    attn_kernel<<<dim3(16,64), 256, 0, stream>>>(qbuf, kbuf, vt, attn);
    gemm_kernel<512,1024,1024,1><<<512, 256, 0, stream>>>(attn, BTproj, x2, nullptr,
        bproj, x, nullptr, nullptr, nullptr);
    ln_kernel<<<8192, 256, 0, stream>>>(x2, ln2_g, ln2_b, h2);
    gemm_kernel<2048,4096,1024,2><<<2048, 256, 0, stream>>>(h2, BT1, nullptr, ff,
        b1, nullptr, nullptr, nullptr, nullptr);
    gemm_kernel<512,1024,4096,1><<<512, 256, 0, stream>>>(ff, BT2, out, nullptr,
        b2, x2, nullptr, nullptr, nullptr);
}

// Round 3
// 650.985 us; speedup vs baseline: 1.3721x; 1.1792x over previous
//
#include <hip/hip_runtime.h>
#include <math.h>

typedef short bf16x8 __attribute__((ext_vector_type(8)));
typedef float f32x4 __attribute__((ext_vector_type(4)));
typedef unsigned short u16;

// ---------------------------------------------------------------- helpers
__device__ __forceinline__ u16 f2bf(float f) {
    union { float f; unsigned u; } v; v.f = f;
    unsigned r = v.u + 0x7fffu + ((v.u >> 16) & 1u);
    return (u16)(r >> 16);
}

__device__ __forceinline__ void gload_lds16(const void* g, void* l) {
    __builtin_amdgcn_global_load_lds((const __attribute__((address_space(1))) void*)g,
                                     (__attribute__((address_space(3))) void*)l, 16, 0, 0);
}

// ---------------------------------------------------------------- transpose+cvt
__global__ __launch_bounds__(256)
void transpose_cvt(const float* __restrict__ in, u16* __restrict__ out, int R, int C)
{
    __shared__ float tile[64][65];
    const size_t slab = (size_t)blockIdx.z * R * C;
    const float* ip = in + slab;
    u16* op = out + slab;
    const int r0 = blockIdx.y * 64, c0 = blockIdx.x * 64;
    const int t = threadIdx.x;
    const int tr = t >> 6, tc = t & 63;
    #pragma unroll
    for (int i = 0; i < 16; ++i)
        tile[tr + i*4][tc] = ip[(size_t)(r0 + tr + i*4)*C + c0 + tc];
    __syncthreads();
    #pragma unroll
    for (int i = 0; i < 16; ++i)
        op[(size_t)(c0 + tr + i*4)*R + r0 + tc] = f2bf(tile[tc][tr + i*4]);
}

// ---------------------------------------------------------------- layernorm
__global__ __launch_bounds__(256)
void ln_kernel(const float* __restrict__ x, const float* __restrict__ g,
               const float* __restrict__ b, u16* __restrict__ out)
{
    const int row = blockIdx.x;
    const int t = threadIdx.x;
    const float4 v = ((const float4*)(x + (size_t)row*1024))[t];
    float s = v.x + v.y + v.z + v.w;
    float ss = v.x*v.x + v.y*v.y + v.z*v.z + v.w*v.w;
    #pragma unroll
    for (int m = 1; m < 64; m <<= 1) {
        s  += __shfl_xor(s, m);
        ss += __shfl_xor(ss, m);
    }
    __shared__ float red[8];
    const int wave = t >> 6;
    if ((t & 63) == 0) { red[wave] = s; red[4 + wave] = ss; }
    __syncthreads();
    s  = red[0] + red[1] + red[2] + red[3];
    ss = red[4] + red[5] + red[6] + red[7];
    const float mu = s * (1.f/1024.f);
    const float rs = rsqrtf(ss * (1.f/1024.f) - mu*mu + 1e-5f);
    const float4 gv = ((const float4*)g)[t];
    const float4 bv = ((const float4*)b)[t];
    ushort4 ov;
    ov.x = f2bf((v.x - mu)*rs*gv.x + bv.x);
    ov.y = f2bf((v.y - mu)*rs*gv.y + bv.y);
    ov.z = f2bf((v.z - mu)*rs*gv.z + bv.z);
    ov.w = f2bf((v.w - mu)*rs*gv.w + bv.w);
    ((ushort4*)(out + (size_t)row*1024))[t] = ov;
}

// ---------------------------------------------------------------- GEMM (m97 structure + XCD swizzle)
template<int NWG, int N, int K, int EPI>
__global__ __launch_bounds__(256)
void gemm_kernel(const u16* __restrict__ A, const u16* __restrict__ BT,
                 float* __restrict__ out_f32, u16* __restrict__ out_bf16,
                 const float* __restrict__ bias, const float* __restrict__ res,
                 u16* __restrict__ qbuf, u16* __restrict__ kbuf, u16* __restrict__ vt)
{
    __shared__ u16 As[128*32];
    __shared__ u16 Bs[128*32];
    const int bid = blockIdx.x;
    const int tid = ((bid & 7) * (NWG / 8)) + (bid >> 3);   // bijective XCD swizzle
    const int m0 = (tid & 63) * 128;
    const int n0 = (tid >> 6) * 128;
    const int t = threadIdx.x;
    const int wave = t >> 6;
    const int lane = t & 63;
    const int l15 = lane & 15, lg = lane >> 4;
    const int wr = wave >> 1, wc = wave & 1;
    f32x4 acc[4][4] = {};

    const int srow = t >> 2;
    const int sce  = (t & 3) * 8;
    for (int k0 = 0; k0 < K; k0 += 32) {
        #pragma unroll
        for (int i = 0; i < 2; ++i) {
            const u16* ga = A  + (size_t)(m0 + i*64 + srow) * K + k0 + sce;
            const u16* gb = BT + (size_t)(n0 + i*64 + srow) * K + k0 + sce;
            gload_lds16(ga, As + i*2048 + wave*512);
            gload_lds16(gb, Bs + i*2048 + wave*512);
        }
        __syncthreads();
        bf16x8 af[4], bfr[4];
        #pragma unroll
        for (int mi = 0; mi < 4; ++mi)
            af[mi] = *(const bf16x8*)(As + (wr*64 + mi*16 + l15)*32 + lg*8);
        #pragma unroll
        for (int ni = 0; ni < 4; ++ni)
            bfr[ni] = *(const bf16x8*)(Bs + (wc*64 + ni*16 + l15)*32 + lg*8);
        #pragma unroll
        for (int mi = 0; mi < 4; ++mi)
            #pragma unroll
            for (int ni = 0; ni < 4; ++ni)
                acc[mi][ni] = __builtin_amdgcn_mfma_f32_16x16x32_bf16(af[mi], bfr[ni], acc[mi][ni], 0, 0, 0);
        __syncthreads();
    }

    #pragma unroll
    for (int mi = 0; mi < 4; ++mi) {
        #pragma unroll
        for (int ni = 0; ni < 4; ++ni) {
            const int gc = n0 + wc*64 + ni*16 + l15;
            #pragma unroll
            for (int j = 0; j < 4; ++j) {
                const int gr = m0 + wr*64 + mi*16 + lg*4 + j;
                float v = acc[mi][ni][j];
                if constexpr (EPI == 0) {
                    u16 bv = f2bf(v);
                    if (gc < 1024) {
                        qbuf[(size_t)gr*1024 + gc] = bv;
                    } else if (gc < 2048) {
                        kbuf[(size_t)gr*1024 + (gc - 1024)] = bv;
                    } else {
                        const int hd = gc - 2048;
                        const int bb = gr >> 11, tt = gr & 2047;
                        vt[(size_t)((bb*16 + (hd >> 6))*64 + (hd & 63))*2048 + tt] = bv;
                    }
                } else if constexpr (EPI == 1) {
                    out_f32[(size_t)gr*N + gc] = v + bias[gc] + res[(size_t)gr*N + gc];
                } else {
                    out_bf16[(size_t)gr*N + gc] = f2bf(fmaxf(v + bias[gc], 0.f));
                }
            }
        }
    }
}

// ---------------------------------------------------------------- flash attention v3
// Load-balanced: block = (pair, bh); q-tiles {pair, 15-pair} (128 q each) share
// K/V staging. Every block does exactly 34 q-tile-iterations.
__device__ __forceinline__ void attn_qtile(
    bf16x8 (&qf)[2][2], f32x4 (&o)[2][4], float (&mprev)[2][4], float (&lsum)[2][4],
    const u16* Ksc, const u16* Vsc, u16* pl,
    int key0, int q0, int l15, int lg, int swzf, int swzp)
{
    #pragma unroll
    for (int mi = 0; mi < 2; ++mi) {
        if (key0 > q0 + mi*16 + 15) continue;   // frag fully masked
        // ---- S = Q K^T
        f32x4 s[4] = {};
        #pragma unroll
        for (int n = 0; n < 4; ++n)
            #pragma unroll
            for (int kk = 0; kk < 2; ++kk) {
                const int row = n*16 + l15;
                bf16x8 kf = *(const bf16x8*)((const char*)Ksc
                                + row*128 + ((kk*64 + lg*16) ^ swzf));
                s[n] = __builtin_amdgcn_mfma_f32_16x16x32_bf16(qf[mi][kk], kf, s[n], 0, 0, 0);
            }
        // ---- mask + scale + row max
        const bool domask = (key0 + 63) > (q0 + mi*16);
        float tm[4] = {-INFINITY, -INFINITY, -INFINITY, -INFINITY};
        #pragma unroll
        for (int n = 0; n < 4; ++n)
            #pragma unroll
            for (int j = 0; j < 4; ++j) {
                float sv = s[n][j] * 0.03125f;
                if (domask && (key0 + n*16 + l15 > q0 + mi*16 + lg*4 + j)) sv = -INFINITY;
                s[n][j] = sv;
                tm[j] = fmaxf(tm[j], sv);
            }
        #pragma unroll
        for (int m = 1; m < 16; m <<= 1)
            #pragma unroll
            for (int j = 0; j < 4; ++j)
                tm[j] = fmaxf(tm[j], __shfl_xor(tm[j], m, 16));
        float alpha[4], rsum[4];
        #pragma unroll
        for (int j = 0; j < 4; ++j) {
            float mn = fmaxf(mprev[mi][j], tm[j]);
            alpha[j] = __expf(mprev[mi][j] - mn);
            mprev[mi][j] = mn;
            rsum[j] = 0.f;
        }
        // ---- P = exp(S - m) -> LDS (swizzled)
        #pragma unroll
        for (int n = 0; n < 4; ++n)
            #pragma unroll
            for (int j = 0; j < 4; ++j) {
                float pv = __expf(s[n][j] - mprev[mi][j]);
                rsum[j] += pv;
                const int qq = lg*4 + j;
                pl[qq*64 + ((n*16 + l15) ^ ((qq & 7) * 8))] = f2bf(pv);
            }
        #pragma unroll
        for (int m = 1; m < 16; m <<= 1)
            #pragma unroll
            for (int j = 0; j < 4; ++j)
                rsum[j] += __shfl_xor(rsum[j], m, 16);
        #pragma unroll
        for (int j = 0; j < 4; ++j)
            lsum[mi][j] = lsum[mi][j]*alpha[j] + rsum[j];
        #pragma unroll
        for (int dn = 0; dn < 4; ++dn)
            #pragma unroll
            for (int j = 0; j < 4; ++j)
                o[mi][dn][j] *= alpha[j];
        // ---- PV
        bf16x8 pf[2];
        #pragma unroll
        for (int kk = 0; kk < 2; ++kk)
            pf[kk] = *(const bf16x8*)(pl + l15*64 + ((kk*32 + lg*8) ^ swzp));
        #pragma unroll
        for (int dn = 0; dn < 4; ++dn)
            #pragma unroll
            for (int kk = 0; kk < 2; ++kk) {
                const int row = dn*16 + l15;
                bf16x8 vf = *(const bf16x8*)((const char*)Vsc
                                + row*128 + ((kk*64 + lg*16) ^ swzf));
                o[mi][dn] = __builtin_amdgcn_mfma_f32_16x16x32_bf16(pf[kk], vf, o[mi][dn], 0, 0, 0);
            }
    }
}

__global__ __launch_bounds__(256, 2)
void attn_kernel(const u16* __restrict__ q, const u16* __restrict__ k,
                 const u16* __restrict__ vt, u16* __restrict__ out)
{
    __shared__ u16 Ks[2][4096];
    __shared__ u16 Vs[2][4096];
    __shared__ u16 Plds[4][1024];

    const int bh = blockIdx.x & 63;         // id%8 == bh%8 -> same-bh blocks share XCD
    const int pair = blockIdx.x >> 6;       // 0..7
    const int b = bh >> 4, h = bh & 15;
    const int wave = threadIdx.x >> 6, lane = threadIdx.x & 63;
    const int l15 = lane & 15, lg = lane >> 4;
    const int qA = pair, qB = 15 - pair;
    const int q0A = qA*128 + wave*32;
    const int q0B = qB*128 + wave*32;
    const u16* Qp = q + (size_t)b*2048*1024 + h*64;
    const u16* Kp = k + (size_t)b*2048*1024 + h*64;
    const u16* Vp = vt + (size_t)bh*64*2048;
    u16* pl = Plds[wave];

    bf16x8 qfA[2][2], qfB[2][2];
    #pragma unroll
    for (int mi = 0; mi < 2; ++mi)
        #pragma unroll
        for (int kk = 0; kk < 2; ++kk) {
            qfA[mi][kk] = *(const bf16x8*)(Qp + (size_t)(q0A + mi*16 + l15)*1024 + kk*32 + lg*8);
            qfB[mi][kk] = *(const bf16x8*)(Qp + (size_t)(q0B + mi*16 + l15)*1024 + kk*32 + lg*8);
        }

    const int srow0 = wave*8 + (lane >> 3);
    const int scol  = ((lane & 7) ^ (srow0 & 7)) << 3;
    const int swzf  = (l15 & 7) << 4;
    const int swzp  = (l15 & 7) << 3;

    f32x4 oA[2][4] = {}, oB[2][4] = {};
    float mprevA[2][4], lsumA[2][4], mprevB[2][4], lsumB[2][4];
    #pragma unroll
    for (int mi = 0; mi < 2; ++mi)
        #pragma unroll
        for (int j = 0; j < 4; ++j) {
            mprevA[mi][j] = -INFINITY; lsumA[mi][j] = 0.f;
            mprevB[mi][j] = -INFINITY; lsumB[mi][j] = 0.f;
        }

    const int nkt = 32 - 2*pair;            // = B's tile count; A's (2*pair+2) <= nkt

    #define STAGE(buf, key0_) do { \
        gload_lds16(Kp + (size_t)((key0_) + srow0)*1024 + scol,      &Ks[buf][wave*512]); \
        gload_lds16(Kp + (size_t)((key0_) + srow0 + 32)*1024 + scol, &Ks[buf][(4+wave)*512]); \
        gload_lds16(Vp + (size_t)srow0*2048 + (key0_) + scol,        &Vs[buf][wave*512]); \
        gload_lds16(Vp + (size_t)(srow0+32)*2048 + (key0_) + scol,   &Vs[buf][(4+wave)*512]); \
    } while (0)

    STAGE(0, 0);

    for (int kt = 0; kt < nkt; ++kt) {
        const int cur = kt & 1;
        const int key0 = kt * 64;
        if (kt + 1 < nkt) {
            STAGE(cur ^ 1, key0 + 64);
            asm volatile("s_waitcnt vmcnt(4)" ::: "memory");
        } else {
            asm volatile("s_waitcnt vmcnt(0)" ::: "memory");
        }
        __builtin_amdgcn_s_barrier();
        __builtin_amdgcn_sched_barrier(0);

        if (key0 <= q0A + 31)
            attn_qtile(qfA, oA, mprevA, lsumA, &Ks[cur][0], &Vs[cur][0], pl,
                       key0, q0A, l15, lg, swzf, swzp);
        if (key0 <= q0B + 31)
            attn_qtile(qfB, oB, mprevB, lsumB, &Ks[cur][0], &Vs[cur][0], pl,
                       key0, q0B, l15, lg, swzf, swzp);

        __builtin_amdgcn_sched_barrier(0);
        __builtin_amdgcn_s_barrier();
    }
    #undef STAGE

    #pragma unroll
    for (int mi = 0; mi < 2; ++mi)
        #pragma unroll
        for (int dn = 0; dn < 4; ++dn)
            #pragma unroll
            for (int j = 0; j < 4; ++j) {
                float vA = oA[mi][dn][j] / lsumA[mi][j];
                out[(size_t)(b*2048 + q0A + mi*16 + lg*4 + j)*1024 + h*64 + dn*16 + l15] = f2bf(vA);
                float vB = oB[mi][dn][j] / lsumB[mi][j];
                out[(size_t)(b*2048 + q0B + mi*16 + lg*4 + j)*1024 + h*64 + dn*16 + l15] = f2bf(vB);
            }
}

// ---------------------------------------------------------------- launch
#define MB(x) ((size_t)(x) << 20)

extern "C" void kernel_launch(void* const* d_in, const int* in_sizes, int n_in,
                              void* d_out, int out_size, void* d_ws, size_t ws_size,
                              hipStream_t stream) {
    const float* x      = (const float*)d_in[0];
    const float* Wq     = (const float*)d_in[1];
    const float* Wk     = (const float*)d_in[2];
    const float* Wv     = (const float*)d_in[3];
    const float* Wproj  = (const float*)d_in[4];
    const float* bproj  = (const float*)d_in[5];
    const float* ln1_g  = (const float*)d_in[6];
    const float* ln1_b  = (const float*)d_in[7];
    const float* ln2_g  = (const float*)d_in[8];
    const float* ln2_b  = (const float*)d_in[9];
    const float* W1     = (const float*)d_in[10];
    const float* b1     = (const float*)d_in[11];
    const float* W2     = (const float*)d_in[12];
    const float* b2     = (const float*)d_in[13];
    float* out = (float*)d_out;

    char* ws = (char*)d_ws;
    u16*  h      = (u16*)(ws + MB(0));
    u16*  qbuf   = (u16*)(ws + MB(16));
    u16*  kbuf   = (u16*)(ws + MB(32));
    u16*  vt     = (u16*)(ws + MB(48));
    u16*  attn   = (u16*)(ws + MB(64));
    float* x2    = (float*)(ws + MB(80));
    u16*  BTqkv  = (u16*)(ws + MB(112));
    u16*  BTproj = (u16*)(ws + MB(118));
    u16*  BT1    = (u16*)(ws + MB(120));
    u16*  BT2    = (u16*)(ws + MB(128));
    u16*  ff     = (u16*)(ws + MB(16));
    u16*  h2     = h;

    transpose_cvt<<<dim3(1,16,16),  256, 0, stream>>>(Wq,    BTqkv,             1024, 64);
    transpose_cvt<<<dim3(1,16,16),  256, 0, stream>>>(Wk,    BTqkv + (1<<20),   1024, 64);
    transpose_cvt<<<dim3(1,16,16),  256, 0, stream>>>(Wv,    BTqkv + (2<<20),   1024, 64);
    transpose_cvt<<<dim3(16,16,1),  256, 0, stream>>>(Wproj, BTproj,            1024, 1024);
    transpose_cvt<<<dim3(64,16,1),  256, 0, stream>>>(W1,    BT1,               1024, 4096);
    transpose_cvt<<<dim3(16,64,1),  256, 0, stream>>>(W2,    BT2,               4096, 1024);

    ln_kernel<<<8192, 256, 0, stream>>>(x, ln1_g, ln1_b, h);
    gemm_kernel<1536,3072,1024,0><<<1536, 256, 0, stream>>>(h, BTqkv, nullptr, nullptr,
        nullptr, nullptr, qbuf, kbuf, vt);
    attn_kernel<<<512, 256, 0, stream>>>(qbuf, kbuf, vt, attn);
    gemm_kernel<512,1024,1024,1><<<512, 256, 0, stream>>>(attn, BTproj, x2, nullptr,
        bproj, x, nullptr, nullptr, nullptr);
    ln_kernel<<<8192, 256, 0, stream>>>(x2, ln2_g, ln2_b, h2);
    gemm_kernel<2048,4096,1024,2><<<2048, 256, 0, stream>>>(h2, BT1, nullptr, ff,
        b1, nullptr, nullptr, nullptr, nullptr);
    gemm_kernel<512,1024,4096,1><<<512, 256, 0, stream>>>(ff, BT2, out, nullptr,
        b2, x2, nullptr, nullptr, nullptr);
}